// Round 10
// baseline (331.968 us; speedup 1.0000x reference)
//
#include <hip/hip_runtime.h>

#define SEQ 4096
#define KDIM 1024
#define NQKV 3072

typedef __bf16 bf16x8 __attribute__((ext_vector_type(8)));
typedef float  f32x4  __attribute__((ext_vector_type(4)));

__device__ __forceinline__ unsigned short f2b(float f) {
    unsigned int u = __float_as_uint(f);
    u += 0x7FFFu + ((u >> 16) & 1u);   // round-to-nearest-even
    return (unsigned short)(u >> 16);
}

// ---------------------------------------------------------------------------
// Register-pipelined 64x64 GEMM, ONE WAVE per block, NO LDS in the main loop.
// A/B fragments load straight global->VGPR (each load covers 16 full 64B
// lines -> same L2 transaction count as coalesced). 4 register stages,
// 3 in flight; no barriers -> no collective vmcnt(0) drains (the R4-R9
// plateau). Compiler emits fine-grained vmcnt(N) from register deps.
// 2x L2 read traffic vs LDS-shared tiles -- affordable at 30% HBM util.
// ---------------------------------------------------------------------------
__device__ __forceinline__ void gemm64_rr(
    const unsigned short* __restrict__ Ag, int lda,
    const unsigned short* __restrict__ Bg, int ldb,
    int kLen, f32x4 acc[4][4])
{
    const int lane = threadIdx.x & 63;
    const int lr = lane & 15, quad = lane >> 4;
    const unsigned short* ap[4];
    const unsigned short* bp[4];
    #pragma unroll
    for (int i = 0; i < 4; ++i) {
        ap[i] = Ag + (16 * i + lr) * lda + quad * 8;
        bp[i] = Bg + (16 * i + lr) * ldb + quad * 8;
    }
    bf16x8 Ab[4][4], Bb[4][4];
    const int niter = kLen >> 5;            // BK=32

#define LOADS(s, off) { \
    _Pragma("unroll") for (int f = 0; f < 4; ++f) { \
        Ab[s][f] = *(const bf16x8*)(ap[f] + (off)); \
        Bb[s][f] = *(const bf16x8*)(bp[f] + (off)); } }
#define COMP(s) { \
    _Pragma("unroll") for (int i = 0; i < 4; ++i) \
    _Pragma("unroll") for (int j = 0; j < 4; ++j) \
        acc[i][j] = __builtin_amdgcn_mfma_f32_16x16x32_bf16(Ab[s][i], Bb[s][j], acc[i][j], 0, 0, 0); }

    LOADS(0, 0);
    if (1 < niter) LOADS(1, 32);
    if (2 < niter) LOADS(2, 64);
    const int kmain = niter & ~3;
    #pragma unroll 1
    for (int k = 0; k < kmain; k += 4) {
        if (k + 3 < niter) LOADS(3, 96);
        COMP(0);
        if (k + 4 < niter) LOADS(0, 128);
        COMP(1);
        if (k + 5 < niter) LOADS(1, 160);
        COMP(2);
        if (k + 6 < niter) LOADS(2, 192);
        COMP(3);
        #pragma unroll
        for (int i = 0; i < 4; ++i) { ap[i] += 128; bp[i] += 128; }
    }
    const int rem = niter - kmain;          // 0..3 (pv kLen can be 64*odd)
    if (rem > 0) COMP(0);
    if (rem > 1) COMP(1);
    if (rem > 2) COMP(2);
#undef LOADS
#undef COMP
}

__device__ __forceinline__ void zero_acc(f32x4 acc[4][4]) {
    const f32x4 z = {0.f, 0.f, 0.f, 0.f};
    #pragma unroll
    for (int i = 0; i < 4; ++i)
        #pragma unroll
        for (int j = 0; j < 4; ++j) acc[i][j] = z;
}

// ---------------------------------------------------------------------------
// Epilogues: wave-private LDS restage -> 16B coalesced bf16 stores.
// (LDS used ONLY here; wave-synchronous, no barriers.)
// ---------------------------------------------------------------------------
__device__ __forceinline__ void store_rows_bf16(
    f32x4 acc[4][4], unsigned short* Cw, int ld, unsigned short* lw, int lane)
{
    const int lr = lane & 15, quad = lane >> 4;
    #pragma unroll
    for (int i = 0; i < 4; ++i) {
        #pragma unroll
        for (int j = 0; j < 4; ++j)
            #pragma unroll
            for (int r = 0; r < 4; ++r)
                lw[(quad * 4 + r) * 72 + j * 16 + lr] = f2b(acc[i][j][r]);
        #pragma unroll
        for (int t = 0; t < 2; ++t) {
            int chunk = t * 64 + lane;          // 0..127
            int rl = chunk >> 3, c8 = chunk & 7;
            uint4 v = *(const uint4*)(lw + rl * 72 + c8 * 8);
            *(uint4*)(Cw + (16 * i + rl) * ld + c8 * 8) = v;
        }
    }
}

// Transposed (Vt[d][s]): wave covers 64 d x 64 s.
__device__ __forceinline__ void store_cols_bf16(
    f32x4 acc[4][4], unsigned short* Vw, unsigned short* lw, int lane)
{
    const int lr = lane & 15, quad = lane >> 4;
    #pragma unroll
    for (int ip = 0; ip < 2; ++ip) {            // 32 s-rows per pass
        #pragma unroll
        for (int ii = 0; ii < 2; ++ii)
            #pragma unroll
            for (int j = 0; j < 4; ++j)
                #pragma unroll
                for (int r = 0; r < 4; ++r)
                    lw[(j * 16 + lr) * 40 + ii * 16 + quad * 4 + r] = f2b(acc[ip * 2 + ii][j][r]);
        #pragma unroll
        for (int t = 0; t < 4; ++t) {
            int chunk = t * 64 + lane;          // 0..255
            int col = chunk >> 2, c8 = chunk & 3;
            uint4 v = *(const uint4*)(lw + col * 40 + c8 * 8);
            *(uint4*)(Vw + col * SEQ + ip * 32 + c8 * 8) = v;
        }
    }
}

// ---------------------------------------------------------------------------
// Kernel 0: fused prep. [0,4096): x->bf16; [4096,8192): zero d_out;
// [8192,11264): W transpose (ushort4 stores); block 11264: zero lrow[4096].
// ---------------------------------------------------------------------------
__global__ __launch_bounds__(256) void prep(
    const float* __restrict__ x, unsigned short* __restrict__ Xb,
    const float* __restrict__ W, unsigned short* __restrict__ Wt,
    float4* __restrict__ out, float4* __restrict__ lrow)
{
    __shared__ float tile[32][33];
    const int b = blockIdx.x, tid = threadIdx.x;
    if (b < 4096) {
        int i = (b * 256 + tid) * 4;
        float4 v = *(const float4*)(x + i);
        ushort4 o;
        o.x = f2b(v.x); o.y = f2b(v.y); o.z = f2b(v.z); o.w = f2b(v.w);
        *(ushort4*)(Xb + i) = o;
    } else if (b < 8192) {
        const float4 z = {0.f, 0.f, 0.f, 0.f};
        out[(b - 4096) * 256 + tid] = z;
    } else if (b < 11264) {
        const int bb = b - 8192;
        const int n0 = (bb % 96) * 32, k0 = (bb / 96) * 32;
        const int c = tid & 31, r0 = tid >> 5;
        #pragma unroll
        for (int r = r0; r < 32; r += 8)
            tile[r][c] = W[(k0 + r) * NQKV + n0 + c];   // tile[k][n]
        __syncthreads();
        const int n = tid >> 3, q = tid & 7;
        ushort4 o;
        o.x = f2b(tile[q * 4 + 0][n]);
        o.y = f2b(tile[q * 4 + 1][n]);
        o.z = f2b(tile[q * 4 + 2][n]);
        o.w = f2b(tile[q * 4 + 3][n]);
        *(ushort4*)(Wt + (n0 + n) * KDIM + k0 + q * 4) = o;
    } else {
        const float4 z = {0.f, 0.f, 0.f, 0.f};
        #pragma unroll
        for (int k = 0; k < 4; ++k) lrow[tid * 4 + k] = z;
    }
}

// ---------------------------------------------------------------------------
// Kernel 1: qvk = Xb @ Wt^T. 64x64 tiles, grid (48 n, 64 m) = 3072 waves.
// ---------------------------------------------------------------------------
__global__ __launch_bounds__(64, 2) void qvk_gemm(
    const unsigned short* __restrict__ Xb, const unsigned short* __restrict__ Wt,
    unsigned short* __restrict__ Qb, unsigned short* __restrict__ Kb,
    unsigned short* __restrict__ Vt)
{
    __shared__ __align__(16) unsigned short lw[2560];
    const int m0 = blockIdx.y * 64;
    const int n0 = blockIdx.x * 64;
    f32x4 acc[4][4];
    zero_acc(acc);
    gemm64_rr(Xb + m0 * KDIM, KDIM, Wt + n0 * KDIM, KDIM, KDIM, acc);

    const int lane = threadIdx.x & 63;
    const int region = n0 >> 10;            // 64-tile never straddles regions
    const int nloc = n0 & 1023;
    if (region == 0)
        store_rows_bf16(acc, Qb + m0 * KDIM + nloc, KDIM, lw, lane);
    else if (region == 2)
        store_rows_bf16(acc, Kb + m0 * KDIM + nloc, KDIM, lw, lane);
    else
        store_cols_bf16(acc, Vt + nloc * SEQ + m0, lw, lane);
}

// ---------------------------------------------------------------------------
// Kernel 2: fused score+exp, 64x64 tiles, exact triangular 1D grid (2080).
// P = exp((Q@K^T)/32) causal (no max-sub: |s|<=16 by Cauchy-Schwarz).
// P stores first, then lrow atomics.
// ---------------------------------------------------------------------------
__global__ __launch_bounds__(64, 2) void score_exp_gemm(
    const unsigned short* __restrict__ Qb, const unsigned short* __restrict__ Kb,
    unsigned short* __restrict__ Sb, float* __restrict__ lrow)
{
    __shared__ __align__(16) unsigned short lw[2560];
    const int b = blockIdx.x;               // 0..2079
    int mi = (int)((sqrtf(8.f * (float)b + 1.f) - 1.f) * 0.5f);
    while ((mi + 1) * (mi + 2) / 2 <= b) ++mi;
    while (mi * (mi + 1) / 2 > b) --mi;
    const int bn = b - mi * (mi + 1) / 2;   // 0..mi
    const int m0 = mi * 64, n0 = bn * 64;

    f32x4 acc[4][4];
    zero_acc(acc);
    gemm64_rr(Qb + m0 * KDIM, KDIM, Kb + n0 * KDIM, KDIM, KDIM, acc);

    const int lane = threadIdx.x & 63;
    const int lr = lane & 15, quad = lane >> 4;
    const bool diag = (bn == mi);
    #pragma unroll
    for (int i = 0; i < 4; ++i)
        #pragma unroll
        for (int j = 0; j < 4; ++j)
            #pragma unroll
            for (int r = 0; r < 4; ++r) {
                float v = __expf(acc[i][j][r] * 0.03125f);
                if (diag) {
                    int row = 16 * i + quad * 4 + r;
                    int col = 16 * j + lr;
                    if (col > row) v = 0.f;
                }
                acc[i][j][r] = v;
            }
    store_rows_bf16(acc, Sb + m0 * SEQ + n0, SEQ, lw, lane);
    #pragma unroll
    for (int i = 0; i < 4; ++i)
        #pragma unroll
        for (int r = 0; r < 4; ++r) {
            float s = acc[i][0][r] + acc[i][1][r] + acc[i][2][r] + acc[i][3][r];
            s += __shfl_xor(s, 1, 16);
            s += __shfl_xor(s, 2, 16);
            s += __shfl_xor(s, 4, 16);
            s += __shfl_xor(s, 8, 16);
            if (lr == 0)
                atomicAdd(&lrow[m0 + 16 * i + quad * 4 + r], s);
        }
}

// ---------------------------------------------------------------------------
// Kernel 3: out = (P @ V) / l. 64-row m-tiles, split-K chunks of 1024
// (atomic depth <=4). Grid (16 n, 160 pairs) = 2560 waves; same-(m,n)
// chunks differ by lin multiples of 16 -> same XCD (atomic locality).
// ---------------------------------------------------------------------------
__global__ __launch_bounds__(64, 2) void pv_gemm(
    const unsigned short* __restrict__ Sb, const unsigned short* __restrict__ Vt,
    const float* __restrict__ lrow, float* __restrict__ out)
{
    const int n0 = blockIdx.x * 64;
    const int y = blockIdx.y;               // 0..159
    int g, base;
    if (y < 16)      { g = 0; base = 0; }
    else if (y < 48) { g = 1; base = 16; }
    else if (y < 96) { g = 2; base = 48; }
    else             { g = 3; base = 96; }
    const int yy = y - base;
    const int mi = 16 * g + yy / (g + 1);
    const int c = yy % (g + 1);
    const int m0 = mi * 64;
    const int kstart = c * 1024;
    const int kend = min(m0 + 64, kstart + 1024);

    f32x4 acc[4][4];
    zero_acc(acc);
    gemm64_rr(Sb + m0 * SEQ + kstart, SEQ, Vt + n0 * SEQ + kstart, SEQ,
              kend - kstart, acc);

    const int lane = threadIdx.x & 63;
    const int lr = lane & 15, quad = lane >> 4;
    #pragma unroll
    for (int i = 0; i < 4; ++i) {
        const int rbase = m0 + 16 * i + quad * 4;
        const float4 l4 = *(const float4*)(lrow + rbase);
        float inv[4] = {1.0f / l4.x, 1.0f / l4.y, 1.0f / l4.z, 1.0f / l4.w};
        #pragma unroll
        for (int j = 0; j < 4; ++j) {
            const int col = n0 + 16 * j + lr;
            if (g == 0) {
                #pragma unroll
                for (int r = 0; r < 4; ++r)
                    out[(rbase + r) * KDIM + col] = acc[i][j][r] * inv[r];
            } else {
                #pragma unroll
                for (int r = 0; r < 4; ++r)
                    atomicAdd(&out[(rbase + r) * KDIM + col], acc[i][j][r] * inv[r]);
            }
        }
    }
}

// ---------------------------------------------------------------------------
extern "C" void kernel_launch(void* const* d_in, const int* in_sizes, int n_in,
                              void* d_out, int out_size, void* d_ws, size_t ws_size,
                              hipStream_t stream) {
    const float* x = (const float*)d_in[0];   // [4096][1024]
    const float* W = (const float*)d_in[1];   // [1024][3072]
    float* out = (float*)d_out;               // [4096][1024]
    char* ws = (char*)d_ws;

    unsigned short* Xb = (unsigned short*)(ws);                     //  8 MiB
    unsigned short* Wt = (unsigned short*)(ws + 8388608);           //  6 MiB
    unsigned short* Qb = (unsigned short*)(ws + 14680064);          //  8 MiB
    unsigned short* Kb = (unsigned short*)(ws + 23068672);          //  8 MiB
    unsigned short* Vt = (unsigned short*)(ws + 31457280);          //  8 MiB
    unsigned short* Sb = (unsigned short*)(ws + 39845888);          // 32 MiB
    float*        lrow = (float*)(ws + 73400320);                   // 16 KiB

    prep          <<<11265, 256, 0, stream>>>(x, Xb, W, Wt, (float4*)out, (float4*)lrow);
    qvk_gemm      <<<dim3(NQKV / 64, SEQ / 64), 64, 0, stream>>>(Xb, Wt, Qb, Kb, Vt);
    score_exp_gemm<<<2080, 64, 0, stream>>>(Qb, Kb, Sb, lrow);
    pv_gemm       <<<dim3(KDIM / 64, 160), 64, 0, stream>>>(Sb, Vt, lrow, out);
}